// Round 7
// baseline (22.609 us; speedup 1.0000x reference)
//
#include <hip/hip_runtime.h>
#include <math.h>

// ---------------------------------------------------------------------------
// WeightedRandomSampler (inverse-CDF multinomial), 2-kernel design:
//   K1 gsum_kernel : coalesced float4 read of freq; 4-lane shfl reduce ->
//                    group sums gsum[G] in ws (G = ceil(V/16) = 3142).
//   K2 sample_kernel: per block: load 12.6KB gsum -> block-scan -> group-CDF
//                    cdfS[G] in LDS; build u16 bucket LUT (K=8192) over key
//                    space by register-chain scatter (exact tiling inside a
//                    thread; linear-guess init + exact bidirectional walk
//                    absorbs any thread-boundary rounding gaps); then each
//                    thread resolves 4 samples: LUT read -> ~0-2 walk steps ->
//                    16-elem group reload (one L2-hot 64B line) prefix-count.
//   Exactness: the walk finds the unique g with cdfS[g-1] <= key < cdfS[g]
//   (cdf strictly increasing, freq > 0), independent of LUT accuracy; the
//   in-group count reproduces searchsorted(cdf, key, 'right') up to blocked-
//   sum rounding (absmax ~256 << 1003 threshold).
// ---------------------------------------------------------------------------

#define GRP 16        // freq elements per group
#define TPB 512       // sampler threads per block (8 waves)
#define SPT 4         // samples per thread
#define GPT_MAX 8     // max groups per thread (V <= 65536)
#define KLUT 8192     // LUT buckets (power of two -> u*KLUT exact)
#define GMAX 4096     // cdfS capacity (V <= 65536)

__global__ __launch_bounds__(256) void gsum_kernel(const float* __restrict__ freq,
                                                   int V, float* __restrict__ gsum) {
    const int i4 = blockIdx.x * 256 + threadIdx.x;   // float4 index
    const int nf4 = (V + 3) >> 2;
    float s = 0.f;
    if (i4 < nf4) {
        const int base = i4 * 4;
        if (base + 3 < V) {
            const float4 v = *reinterpret_cast<const float4*>(freq + base);
            s = v.x + v.y + v.z + v.w;
        } else {
            for (int j = 0; j < 4; ++j)
                if (base + j < V) s += freq[base + j];
        }
    }
    // 4 consecutive lanes (aligned quads) hold one 16-elem group
    s += __shfl_xor(s, 1);
    s += __shfl_xor(s, 2);
    const int g = i4 >> 2;
    const int G = (V + GRP - 1) / GRP;
    if ((threadIdx.x & 3) == 0 && g < G) gsum[g] = s;
}

__global__ __launch_bounds__(TPB) void sample_kernel(const float* __restrict__ freq,
                                                     const float* __restrict__ u,
                                                     const float* __restrict__ gsum,
                                                     float* __restrict__ out,
                                                     int N, int V, int G) {
    __shared__ float cdfS[GMAX];
    __shared__ unsigned short lut[KLUT + 1];
    __shared__ float wsum[TPB / 64];
    const int t = threadIdx.x;
    const int lane = t & 63;
    const int w = t >> 6;
    const int GPT = (G + TPB - 1) / TPB;   // 7 for G=3142

    // ---- phase A: block scan of group sums ----
    const int g0 = t * GPT;
    float ls[GPT_MAX];                     // compile-time indexed
    float runv = 0.f;
#pragma unroll
    for (int k = 0; k < GPT_MAX; ++k) {
        float s = 0.f;
        if (k < GPT) { const int g = g0 + k; if (g < G) s = gsum[g]; }
        runv += s;
        ls[k] = runv;
    }
    float sc = runv;                       // wave-inclusive scan of totals
#pragma unroll
    for (int off = 1; off <= 32; off <<= 1) {
        const float v = __shfl_up(sc, off);
        if (lane >= off) sc += v;
    }
    if (lane == 63) wsum[w] = sc;
    __syncthreads();
    float tbase = sc - runv;               // exclusive base for this thread
    for (int k = 0; k < w; ++k) tbase += wsum[k];

#pragma unroll
    for (int k = 0; k < GPT_MAX; ++k) {
        if (k < GPT) { const int g = g0 + k; if (g < G) cdfS[g] = tbase + ls[k]; }
    }
    // linear-guess LUT init (covers any scatter gaps; walk makes it exact)
    for (int b = t; b <= KLUT; b += TPB) {
        int gg = (int)(((long long)b * G) >> 13);    // b*G/8192
        lut[b] = (unsigned short)((gg > G - 1) ? (G - 1) : gg);
    }
    __syncthreads();

    const float total = cdfS[G - 1];
    const float fK = (float)KLUT;

    // ---- phase B: scatter LUT from the register-resident chain ----
    {
        float cprev = tbase;
#pragma unroll
        for (int k = 0; k < GPT_MAX; ++k) {
            if (k < GPT) {
                const int g = g0 + k;
                if (g < G) {
                    const float ccur = tbase + ls[k];
                    int bl = (int)ceilf(fK * (cprev / total));
                    int bh = (int)ceilf(fK * (ccur / total));
                    bl = bl < 0 ? 0 : (bl > KLUT ? KLUT : bl);
                    bh = bh < 0 ? 0 : (bh > KLUT ? KLUT : bh);
                    for (int b = bl; b < bh; ++b) lut[b] = (unsigned short)g;
                    cprev = ccur;
                }
            }
        }
    }
    __syncthreads();

    // ---- phase C: sample ----
    const int gid = blockIdx.x * TPB + t;
    const long long i0 = (long long)gid * SPT;
    if (i0 >= N) return;                   // after all barriers

    float uk[SPT];
    if (i0 + SPT <= N) {
        const float4 A = *reinterpret_cast<const float4*>(u + i0);
        uk[0] = A.x; uk[1] = A.y; uk[2] = A.z; uk[3] = A.w;
    } else {
#pragma unroll
        for (int s = 0; s < SPT; ++s) uk[s] = (i0 + s < N) ? u[i0 + s] : 0.f;
    }

    float ok[SPT];
#pragma unroll
    for (int s = 0; s < SPT; ++s) {
        const float key = uk[s] * total;
        int b = (int)(uk[s] * fK);         // exact: fK power of two, u in [0,1)
        b = b < 0 ? 0 : (b > KLUT - 1 ? KLUT - 1 : b);
        int g = lut[b];
        g = (g > G - 1) ? (G - 1) : g;
        // exact bidirectional walk: unique g with cdfS[g-1] <= key < cdfS[g]
        while (g < G - 1 && cdfS[g] <= key) ++g;
        while (g > 0 && cdfS[g - 1] > key) --g;
        const float base = (g > 0) ? cdfS[g - 1] : 0.f;
        const int eb = g * GRP;

        float r = base;
        int cnt = 0;
        if (eb + GRP <= V) {
            const float4* fp = reinterpret_cast<const float4*>(freq + eb);
            const float4 a = fp[0], bb = fp[1], c = fp[2], d = fp[3];
            r += a.x;  cnt += (r <= key); r += a.y;  cnt += (r <= key);
            r += a.z;  cnt += (r <= key); r += a.w;  cnt += (r <= key);
            r += bb.x; cnt += (r <= key); r += bb.y; cnt += (r <= key);
            r += bb.z; cnt += (r <= key); r += bb.w; cnt += (r <= key);
            r += c.x;  cnt += (r <= key); r += c.y;  cnt += (r <= key);
            r += c.z;  cnt += (r <= key); r += c.w;  cnt += (r <= key);
            r += d.x;  cnt += (r <= key); r += d.y;  cnt += (r <= key);
            r += d.z;  cnt += (r <= key); r += d.w;  cnt += (r <= key);
        } else {
            for (int j = 0; j < GRP; ++j) {
                const int idx = eb + j;
                if (idx < V) { r += freq[idx]; cnt += (r <= key); }
            }
        }
        int ans = eb + cnt;                // searchsorted 'right'
        ans = (ans > V - 1) ? (V - 1) : ans;
        ok[s] = (float)ans;
    }

    if (i0 + SPT <= N) {
        *reinterpret_cast<float4*>(out + i0) = make_float4(ok[0], ok[1], ok[2], ok[3]);
    } else {
        for (int s = 0; s < SPT; ++s)
            if (i0 + s < N) out[i0 + s] = ok[s];
    }
}

extern "C" void kernel_launch(void* const* d_in, const int* in_sizes, int n_in,
                              void* d_out, int out_size, void* d_ws, size_t ws_size,
                              hipStream_t stream) {
    const float* freq = (const float*)d_in[0];
    const float* u    = (const float*)d_in[1];
    float* out        = (float*)d_out;
    const int V = in_sizes[0];
    const int N = in_sizes[1];
    const int G = (V + GRP - 1) / GRP;                 // 3142 for V=50257

    float* gsum = (float*)d_ws;                        // G floats

    const int nf4 = (V + 3) >> 2;
    hipLaunchKernelGGL(gsum_kernel, dim3((nf4 + 255) / 256), dim3(256), 0, stream,
                       freq, V, gsum);

    const int NB = (N + TPB * SPT - 1) / (TPB * SPT);  // 512 for N=2^20
    hipLaunchKernelGGL(sample_kernel, dim3(NB), dim3(TPB), 0, stream,
                       freq, u, gsum, out, N, V, G);
}

// Round 8
// 19.828 us; speedup vs baseline: 1.1402x; 1.1402x over previous
//
#include <hip/hip_runtime.h>
#include <math.h>

// ---------------------------------------------------------------------------
// WeightedRandomSampler (inverse-CDF multinomial), 2-kernel design:
//   K1 gsum_kernel  : coalesced float4 read of freq; 4-lane shfl reduce ->
//                     group sums gsum[G] in ws (G = ceil(V/16) = 3142).
//   K2 sample_kernel: per block: load 12.6KB gsum -> block scan -> group-CDF
//                     in LDS, padded layout phys(i) = i + i/32 (binary-search
//                     strides are powers of two; padding de-conflicts banks).
//                     Per sample: 12-level branchless LDS bsearch -> group g;
//                     reload that group's 16 freqs (one L2-hot 64B line),
//                     sequential prefix + compare-count -> exact
//                     searchsorted(cdf, key, 'right'); clip; float out.
//   vs round 6 (19.3us): phase-1 redundancy removed (12.6KB vs 200KB/block,
//     7-add vs 112-add serial ramp); SPT 8->4 doubles blocks/CU for probe
//     latency hiding; u-load hoisted above the scan.
//   vs round 7 (22.6us): no LUT scatter (divergent, LDS-op-neutral).
// ---------------------------------------------------------------------------

#define GRP 16        // freq elements per group
#define TPB 512       // sampler threads per block (8 waves)
#define SPT 4         // samples per thread -> 512 blocks for N=2^20
#define GPT_MAX 16    // max groups per thread (supports G <= 8192)

__device__ __forceinline__ int physIdx(int i) { return i + (i >> 5); }

__global__ __launch_bounds__(256) void gsum_kernel(const float* __restrict__ freq,
                                                   int V, float* __restrict__ gsum) {
    const int i4 = blockIdx.x * 256 + threadIdx.x;   // float4 index
    const int nf4 = (V + 3) >> 2;
    float s = 0.f;
    if (i4 < nf4) {
        const int base = i4 * 4;
        if (base + 3 < V) {
            const float4 v = *reinterpret_cast<const float4*>(freq + base);
            s = v.x + v.y + v.z + v.w;
        } else {
            for (int j = 0; j < 4; ++j)
                if (base + j < V) s += freq[base + j];
        }
    }
    // 4 consecutive lanes (aligned quads) hold one 16-elem group
    s += __shfl_xor(s, 1);
    s += __shfl_xor(s, 2);
    const int g = i4 >> 2;
    const int G = (V + GRP - 1) / GRP;
    if ((threadIdx.x & 3) == 0 && g < G) gsum[g] = s;
}

template <int PAD>
__global__ __launch_bounds__(TPB) void sample_kernel(const float* __restrict__ freq,
                                                     const float* __restrict__ u,
                                                     const float* __restrict__ gsum,
                                                     float* __restrict__ out,
                                                     int N, int V, int G) {
    __shared__ float sS[PAD + (PAD >> 5)];   // padded group-CDF
    __shared__ float wsum[TPB / 64];
    const int t = threadIdx.x;
    const int lane = t & 63;
    const int w = t >> 6;
    const int GPT = (G + TPB - 1) / TPB;     // 7 for G=3142

    // hoisted sample load: issue the HBM read before the scan so its latency
    // hides under phase A (it cannot be hoisted past __syncthreads by hipcc)
    const int gid = blockIdx.x * TPB + t;
    const long long i0 = (long long)gid * SPT;
    float uk[SPT];
    const bool full = (i0 + SPT <= N);
    if (full) {
        const float4 A = *reinterpret_cast<const float4*>(u + i0);
        uk[0] = A.x; uk[1] = A.y; uk[2] = A.z; uk[3] = A.w;
    } else {
#pragma unroll
        for (int s = 0; s < SPT; ++s) uk[s] = (i0 + s < N) ? u[i0 + s] : 0.f;
    }

    // ---- phase A: block scan of group sums ----
    const int g0 = t * GPT;
    float ls[GPT_MAX];                       // compile-time indexed
    float runv = 0.f;
#pragma unroll
    for (int k = 0; k < GPT_MAX; ++k) {
        float s = 0.f;
        if (k < GPT) { const int g = g0 + k; if (g < G) s = gsum[g]; }
        runv += s;
        ls[k] = runv;
    }
    float sc = runv;                         // wave-inclusive scan of totals
#pragma unroll
    for (int off = 1; off <= 32; off <<= 1) {
        const float v = __shfl_up(sc, off);
        if (lane >= off) sc += v;
    }
    if (lane == 63) wsum[w] = sc;
    __syncthreads();
    float tbase = sc - runv;                 // exclusive base for this thread
    for (int k = 0; k < w; ++k) tbase += wsum[k];

#pragma unroll
    for (int k = 0; k < GPT_MAX; ++k) {
        if (k < GPT) { const int g = g0 + k; if (g < G) sS[physIdx(g)] = tbase + ls[k]; }
    }
    for (int i = G + t; i < PAD; i += TPB) sS[physIdx(i)] = INFINITY;  // pads
    __syncthreads();

    if (i0 >= N) return;                     // after all barriers

    const float total = sS[physIdx(G - 1)];  // broadcast LDS read

    // ---- phase B: sample ----
    float ok[SPT];
#pragma unroll
    for (int s = 0; s < SPT; ++s) {
        const float key = uk[s] * total;

        // branchless "count of entries <= key" over PAD sorted values
        int pos = -1;
#pragma unroll
        for (int step = PAD >> 1; step >= 1; step >>= 1) {
            const int j = pos + step;
            pos += (sS[physIdx(j)] <= key) ? step : 0;
        }
        int g = pos + 1;                     // group holding the boundary
        g = (g > G - 1) ? (G - 1) : g;
        const float base = (g > 0) ? sS[physIdx(g - 1)] : 0.f;
        const int eb = g * GRP;

        float r = base;
        int cnt = 0;
        if (eb + GRP <= V) {
            const float4* fp = reinterpret_cast<const float4*>(freq + eb);
            const float4 a = fp[0], b = fp[1], c = fp[2], d = fp[3];
            r += a.x; cnt += (r <= key); r += a.y; cnt += (r <= key);
            r += a.z; cnt += (r <= key); r += a.w; cnt += (r <= key);
            r += b.x; cnt += (r <= key); r += b.y; cnt += (r <= key);
            r += b.z; cnt += (r <= key); r += b.w; cnt += (r <= key);
            r += c.x; cnt += (r <= key); r += c.y; cnt += (r <= key);
            r += c.z; cnt += (r <= key); r += c.w; cnt += (r <= key);
            r += d.x; cnt += (r <= key); r += d.y; cnt += (r <= key);
            r += d.z; cnt += (r <= key); r += d.w; cnt += (r <= key);
        } else {                             // tail group, guarded
            for (int j = 0; j < GRP; ++j) {
                const int idx = eb + j;
                if (idx < V) { r += freq[idx]; cnt += (r <= key); }
            }
        }
        int ans = eb + cnt;                  // searchsorted 'right'
        ans = (ans > V - 1) ? (V - 1) : ans; // clip like reference
        ok[s] = (float)ans;
    }

    if (full) {
        *reinterpret_cast<float4*>(out + i0) = make_float4(ok[0], ok[1], ok[2], ok[3]);
    } else {
        for (int s = 0; s < SPT; ++s)
            if (i0 + s < N) out[i0 + s] = ok[s];
    }
}

extern "C" void kernel_launch(void* const* d_in, const int* in_sizes, int n_in,
                              void* d_out, int out_size, void* d_ws, size_t ws_size,
                              hipStream_t stream) {
    const float* freq = (const float*)d_in[0];
    const float* u    = (const float*)d_in[1];
    float* out        = (float*)d_out;
    const int V = in_sizes[0];
    const int N = in_sizes[1];
    const int G = (V + GRP - 1) / GRP;                 // 3142 for V=50257

    float* gsum = (float*)d_ws;                        // G floats in ws

    const int nf4 = (V + 3) >> 2;
    hipLaunchKernelGGL(gsum_kernel, dim3((nf4 + 255) / 256), dim3(256), 0, stream,
                       freq, V, gsum);

    const int NB = (N + TPB * SPT - 1) / (TPB * SPT);  // 512 for N=2^20
    if (G < 1024) {
        hipLaunchKernelGGL(sample_kernel<1024>, dim3(NB), dim3(TPB), 0, stream,
                           freq, u, gsum, out, N, V, G);
    } else if (G < 2048) {
        hipLaunchKernelGGL(sample_kernel<2048>, dim3(NB), dim3(TPB), 0, stream,
                           freq, u, gsum, out, N, V, G);
    } else if (G < 4096) {
        hipLaunchKernelGGL(sample_kernel<4096>, dim3(NB), dim3(TPB), 0, stream,
                           freq, u, gsum, out, N, V, G);
    } else {
        hipLaunchKernelGGL(sample_kernel<8192>, dim3(NB), dim3(TPB), 0, stream,
                           freq, u, gsum, out, N, V, G);
    }
}